// Round 4
// baseline (3334.675 us; speedup 1.0000x reference)
//
#include <hip/hip_runtime.h>
#include <math.h>

#define MQ 512           // states q
#define ML 512           // sequence length L
#define MS 26            // symbols
#define MB 32            // batch
#define MM 2             // models
#define NPOST (MM*MB*ML*MQ)   // 16777216

// ws layout (floats)
#define OFF_A    0
#define OFF_APK  (OFF_A + MM*MQ*MQ)         // uint32: [m][256 pairs][512 j]
#define OFF_ATPK (OFF_APK + MM*256*MQ)
#define OFF_B    (OFF_ATPK + MM*256*MQ)
#define OFF_INIT (OFF_B + MM*MQ*MS)
#define OFF_E    (OFF_INIT + MM*MQ)
#define OFF_P1   (OFF_E + NPOST)
#define OFF_LL   (OFF_P1 + NPOST)

#define LOG16f   2.7725887222397811f
#define LOG4096f 8.3177661667193433f

typedef _Float16 halfx2 __attribute__((ext_vector_type(2)));

#define BCH(x) __builtin_bit_cast(halfx2, (unsigned)(x))

#if __has_builtin(__builtin_amdgcn_fdot2)
#define FDOT2(a,b,c) __builtin_amdgcn_fdot2((a),(b),(c),false)
#else
static __device__ __forceinline__ float FDOT2(halfx2 a, halfx2 b, float c){
  return fmaf((float)a.x,(float)b.x, fmaf((float)a.y,(float)b.y,c));
}
#endif

#if __has_builtin(__builtin_amdgcn_cvt_pkrtz)
#define PKU(x,y) __builtin_bit_cast(unsigned, __builtin_amdgcn_cvt_pkrtz((x),(y)))
#else
static __device__ __forceinline__ unsigned PKU(float x, float y){
  halfx2 r; r.x=(_Float16)x; r.y=(_Float16)y; return __builtin_bit_cast(unsigned, r);
}
#endif

// ---------------- row softmax of transition logits -> A (prob domain) ----------------
__global__ void k_softmaxA(const float* __restrict__ tl, float* __restrict__ A) {
    int row = blockIdx.x;                       // m*512 + i
    const float* x = tl + (size_t)row * MQ;
    float* y = A + (size_t)row * MQ;
    int tid = threadIdx.x;                      // 256 threads
    float v0 = x[tid], v1 = x[tid + 256];
    float mx = fmaxf(v0, v1);
    #pragma unroll
    for (int d = 32; d >= 1; d >>= 1) mx = fmaxf(mx, __shfl_xor(mx, d));
    __shared__ float sm[4], ss[4];
    int w = tid >> 6;
    if ((tid & 63) == 0) sm[w] = mx;
    __syncthreads();
    mx = fmaxf(fmaxf(sm[0], sm[1]), fmaxf(sm[2], sm[3]));
    float e0 = expf(v0 - mx), e1 = expf(v1 - mx);
    float s = e0 + e1;
    #pragma unroll
    for (int d = 32; d >= 1; d >>= 1) s += __shfl_xor(s, d);
    if ((tid & 63) == 0) ss[w] = s;
    __syncthreads();
    s = ss[0] + ss[1] + ss[2] + ss[3];
    float inv = 1.0f / s;
    y[tid] = e0 * inv;
    y[tid + 256] = e1 * inv;
}

// ---------------- pack A (prob fp32) -> fp16 pairs along i, scaled x16 ----------------
__global__ void k_packA(const float* __restrict__ A, unsigned* __restrict__ Apk) {
    int P = blockIdx.x, m = blockIdx.y, j = threadIdx.x;   // 512 threads
    const float* s = A + ((size_t)(m*MQ) + 2*P) * MQ;
    float x0 = s[j] * 16.f, x1 = s[MQ + j] * 16.f;
    halfx2 r; r.x = (_Float16)x0; r.y = (_Float16)x1;
    Apk[((size_t)m*256 + P) * MQ + j] = __builtin_bit_cast(unsigned, r);
}

// ---------------- transpose A and pack pairs along j (for backward), scaled x16 -------
__global__ void k_transposePack(const float* __restrict__ A, unsigned* __restrict__ ATpk) {
    __shared__ float tile[64][65];
    int m = blockIdx.z;
    int i0 = blockIdx.x * 64, j0 = blockIdx.y * 64;
    int tx = threadIdx.x, ty = threadIdx.y;     // (64,4)
    for (int r = ty; r < 64; r += 4)
        tile[r][tx] = A[((size_t)(m*MQ + i0 + r))*MQ + j0 + tx];
    __syncthreads();
    for (int rp = ty; rp < 32; rp += 4) {
        float x0 = tile[tx][2*rp]   * 16.f;
        float x1 = tile[tx][2*rp+1] * 16.f;
        halfx2 r; r.x = (_Float16)x0; r.y = (_Float16)x1;
        ATpk[((size_t)m*256 + (j0>>1) + rp) * MQ + i0 + tx] = __builtin_bit_cast(unsigned, r);
    }
}

// ---------------- emission softmax (B) + init softmax ----------------
__global__ void k_bprep(const float* __restrict__ emis, const float* __restrict__ initl,
                        float* __restrict__ Bmat, float* __restrict__ initp) {
    int m = blockIdx.x;
    int q = threadIdx.x;                        // 512 threads
    const float* er = emis + ((size_t)(m*MQ) + q) * MS;
    float tv[MS];
    float mx = -1e30f;
    #pragma unroll
    for (int s = 0; s < MS; s++) { tv[s] = er[s]; mx = fmaxf(mx, tv[s]); }
    float sum = 0.f;
    #pragma unroll
    for (int s = 0; s < MS; s++) { tv[s] = expf(tv[s] - mx); sum += tv[s]; }
    float inv = 1.f / sum;
    float* bo = Bmat + ((size_t)(m*MQ) + q) * MS;
    #pragma unroll
    for (int s = 0; s < MS; s++) bo[s] = tv[s] * inv;

    __shared__ float red2[8];
    float v = initl[m*MQ + q];
    float mx2 = v;
    #pragma unroll
    for (int d = 32; d >= 1; d >>= 1) mx2 = fmaxf(mx2, __shfl_xor(mx2, d));
    if ((q & 63) == 0) red2[q >> 6] = mx2;
    __syncthreads();
    mx2 = red2[0];
    #pragma unroll
    for (int k = 1; k < 8; k++) mx2 = fmaxf(mx2, red2[k]);
    float e = expf(v - mx2);
    float s2 = e;
    #pragma unroll
    for (int d = 32; d >= 1; d >>= 1) s2 += __shfl_xor(s2, d);
    __syncthreads();
    if ((q & 63) == 0) red2[q >> 6] = s2;
    __syncthreads();
    s2 = 0.f;
    #pragma unroll
    for (int k = 0; k < 8; k++) s2 += red2[k];
    initp[m*MQ + q] = e / s2;
}

// ---------------- E[m,b,l,q] = sum_s inputs[m,b,l,s]*B[m,q,s] + EPS ----------------
__global__ void k_ekernel(const float* __restrict__ inp, const float* __restrict__ Bmat,
                          float* __restrict__ E) {
    int lc = blockIdx.x, b = blockIdx.y, m = blockIdx.z;
    int tid = threadIdx.x;                      // 512
    __shared__ float Bl[MQ * MS];               // 53KB
    __shared__ float xl[8 * MS];
    for (int k = tid; k < MQ * MS; k += 512) Bl[k] = Bmat[(size_t)m * MQ * MS + k];
    int l0 = lc * 8;
    const float* xin = inp + (((size_t)(m*MB + b) * ML + l0) * MS);
    for (int k = tid; k < 8 * MS; k += 512) xl[k] = xin[k];
    __syncthreads();
    float* Eo = E + (((size_t)(m*MB + b) * ML + l0) * MQ);
    const float* br = Bl + tid * MS;
    for (int l = 0; l < 8; l++) {
        float acc = 1e-16f;
        const float* xr = xl + l * MS;
        #pragma unroll
        for (int s = 0; s < MS; s++) acc = fmaf(br[s], xr[s], acc);
        Eo[l * MQ + tid] = acc;
    }
}

// ---------------- fused fwd/bwd: 64 blocks (dir,m,bpair) x 256 threads, 2 chains ------
// Per-lane tile: 64 i (32 fp16 pairs) x 16 j, shared by both chains.
// Pairs 0..20 in VGPRs (336 regs), 21..23 in LDS slabs, 24..31 streamed from L2
// through a rotating 3-buffer (48 regs in flight) — peak live ~478 < 512, no scratch.
// lane = ig*8+jg (wave w); wave owns j in [128w,128w+128); lane i-range [64ig,64ig+64).

#define NREGP 21
#define SLAB_ROWS 24           // 8 ig * 3 pairs (21,22,23)
#define SLAB_STR  524          // stride%32=12 -> conflict-free b128
#define ABASE (SLAB_ROWS*SLAB_STR)    // 12576
#define ACH   288                     // per-chain alpha region (8 groups * 36)
#define RBASE (ABASE + 2*ACH)         // 13152
#define SHM_DW (RBASE + 16)           // 13168 dwords = 52672 B

#define D2C(idx, AW) { u0[idx]=FDOT2(BCH(AW),_ah0,u0[idx]); u1[idx]=FDOT2(BCH(AW),_ah1,u1[idx]); }

#define DOT16_2(A0,A1,A2,A3, AD0, AD1) do { halfx2 _ah0 = BCH(AD0), _ah1 = BCH(AD1); \
  D2C(0,(A0).x)  D2C(1,(A0).y)  D2C(2,(A0).z)  D2C(3,(A0).w)                         \
  D2C(4,(A1).x)  D2C(5,(A1).y)  D2C(6,(A1).z)  D2C(7,(A1).w)                         \
  D2C(8,(A2).x)  D2C(9,(A2).y)  D2C(10,(A2).z) D2C(11,(A2).w)                        \
  D2C(12,(A3).x) D2C(13,(A3).y) D2C(14,(A3).z) D2C(15,(A3).w)                        \
} while(0)

#define LOADSV(DST, PI) do {                                                  \
  DST[0] = gM4[((PI)*128) + wj4 + 0]; DST[1] = gM4[((PI)*128) + wj4 + 1];     \
  DST[2] = gM4[((PI)*128) + wj4 + 2]; DST[3] = gM4[((PI)*128) + wj4 + 3];     \
} while(0)

#define SLABDOT(S, AD0, AD1) do {                                             \
  const unsigned* _sp = shm + (ig*3+(S))*SLAB_STR + wbase + jg*16;            \
  uint4 _sd0 = *(const uint4*)(_sp + 0);                                      \
  uint4 _sd1 = *(const uint4*)(_sp + 4);                                      \
  uint4 _sd2 = *(const uint4*)(_sp + 8);                                      \
  uint4 _sd3 = *(const uint4*)(_sp + 12);                                     \
  DOT16_2(_sd0,_sd1,_sd2,_sd3, AD0, AD1);                                     \
} while(0)

// matvec + reduce: MV00,MV01 = chain0 column sums at j=jown,jown+1; MV10,MV11 chain1
// Stream schedule (pairs 24..31 via rotating sb0/sb1/sb2):
//   prologue: sb0<-24 sb1<-25 sb2<-26
//   p==8:  dot sb0(24,q6.x), sb0<-27 | p==11: dot sb1(25,q6.y), sb1<-28
//   p==14: dot sb2(26,q6.z), sb2<-29 | p==17: dot sb0(27,q6.w), sb0<-30
//   p==20: dot sb1(28,q7.x), sb1<-31
//   tail: dot sb2(29,q7.y), slab0(21,t0.y), dot sb0(30,q7.z), slab1(22,t0.z),
//         dot sb1(31,q7.w), slab2(23,t0.w)
#define MATVEC(MV00, MV01, MV10, MV11) do {                                   \
  float u0[16], u1[16];                                                       \
  _Pragma("unroll") for (int k=0;k<16;k++){ u0[k]=0.f; u1[k]=0.f; }           \
  const unsigned* al0 = shm + ABASE + ig*36;                                  \
  const unsigned* al1 = shm + ABASE + ACH + ig*36;                            \
  uint4 q6a = *(const uint4*)(al0 + 24), q6b = *(const uint4*)(al1 + 24);     \
  uint4 q7a = *(const uint4*)(al0 + 28), q7b = *(const uint4*)(al1 + 28);     \
  uint4 sb0[4], sb1[4], sb2[4];                                               \
  LOADSV(sb0, ig*32+24); LOADSV(sb1, ig*32+25); LOADSV(sb2, ig*32+26);        \
  uint4 t0, t1;                                                               \
  _Pragma("unroll")                                                           \
  for (int p=0;p<NREGP;++p){                                                  \
    if ((p&3)==0){ t0 = *(const uint4*)(al0 + p); t1 = *(const uint4*)(al1 + p); } \
    unsigned ad0 = ((p&3)==0)?t0.x:((p&3)==1)?t0.y:((p&3)==2)?t0.z:t0.w;      \
    unsigned ad1 = ((p&3)==0)?t1.x:((p&3)==1)?t1.y:((p&3)==2)?t1.z:t1.w;      \
    DOT16_2(Ar[p*4+0],Ar[p*4+1],Ar[p*4+2],Ar[p*4+3], ad0, ad1);               \
    if (p==8){  DOT16_2(sb0[0],sb0[1],sb0[2],sb0[3], q6a.x, q6b.x);           \
                LOADSV(sb0, ig*32+27); }                                      \
    if (p==11){ DOT16_2(sb1[0],sb1[1],sb1[2],sb1[3], q6a.y, q6b.y);           \
                LOADSV(sb1, ig*32+28); }                                      \
    if (p==14){ DOT16_2(sb2[0],sb2[1],sb2[2],sb2[3], q6a.z, q6b.z);           \
                LOADSV(sb2, ig*32+29); }                                      \
    if (p==17){ DOT16_2(sb0[0],sb0[1],sb0[2],sb0[3], q6a.w, q6b.w);           \
                LOADSV(sb0, ig*32+30); }                                      \
    if (p==20){ DOT16_2(sb1[0],sb1[1],sb1[2],sb1[3], q7a.x, q7b.x);           \
                LOADSV(sb1, ig*32+31); }                                      \
  }                                                                           \
  DOT16_2(sb2[0],sb2[1],sb2[2],sb2[3], q7a.y, q7b.y);                         \
  SLABDOT(0, t0.y, t1.y);                                                     \
  DOT16_2(sb0[0],sb0[1],sb0[2],sb0[3], q7a.z, q7b.z);                         \
  SLABDOT(1, t0.z, t1.z);                                                     \
  DOT16_2(sb1[0],sb1[1],sb1[2],sb1[3], q7a.w, q7b.w);                         \
  SLABDOT(2, t0.w, t1.w);                                                     \
  float v8a[8], v8b[8];                                                       \
  { const int h=(ig>>2)&1;                                                    \
    _Pragma("unroll") for (int k=0;k<8;k++){                                  \
      float ma = h?u0[k+8]:u0[k];  float oa = h?u0[k]:u0[k+8];                \
      v8a[k] = ma + __shfl_xor(oa,32);                                        \
      float mb = h?u1[k+8]:u1[k];  float ob = h?u1[k]:u1[k+8];                \
      v8b[k] = mb + __shfl_xor(ob,32); } }                                    \
  float v4a[4], v4b[4];                                                       \
  { const int h=(ig>>1)&1;                                                    \
    _Pragma("unroll") for (int k=0;k<4;k++){                                  \
      float ma = h?v8a[k+4]:v8a[k]; float oa = h?v8a[k]:v8a[k+4];             \
      v4a[k] = ma + __shfl_xor(oa,16);                                        \
      float mb = h?v8b[k+4]:v8b[k]; float ob = h?v8b[k]:v8b[k+4];             \
      v4b[k] = mb + __shfl_xor(ob,16); } }                                    \
  { const int h=ig&1;                                                         \
    float m0 = h?v4a[2]:v4a[0], o0 = h?v4a[0]:v4a[2];                         \
    float m1 = h?v4a[3]:v4a[1], o1 = h?v4a[1]:v4a[3];                         \
    MV00 = m0 + __shfl_xor(o0,8); MV01 = m1 + __shfl_xor(o1,8);               \
    float m2 = h?v4b[2]:v4b[0], o2 = h?v4b[0]:v4b[2];                         \
    float m3 = h?v4b[3]:v4b[1], o3 = h?v4b[1]:v4b[3];                         \
    MV10 = m2 + __shfl_xor(o2,8); MV11 = m3 + __shfl_xor(o3,8); }             \
} while(0)

__global__ __launch_bounds__(256, 1) void k_fwdbwd(
    const unsigned* __restrict__ Apk, const unsigned* __restrict__ ATpk,
    const float* __restrict__ E, const float* __restrict__ initp,
    float* __restrict__ P1, float* __restrict__ out, float* __restrict__ llws)
{
    __shared__ __align__(16) unsigned shm[SHM_DW];
    const int bid = blockIdx.x;
    const int dir = bid & 1, m = (bid >> 1) & 1;
    const int b0 = (bid >> 2) * 2;
    const int tid = threadIdx.x;
    const int w = tid >> 6, lane = tid & 63;
    const int ig = lane >> 3, jg = lane & 7;
    const int wbase = w * 128;
    const int jown = wbase + jg*16 + ig*2;
    const int wj4 = (wbase + jg*16) >> 2;
    const int Pown = jown >> 1;
    const int aown = (Pown >> 5)*36 + (Pown & 31);

    const unsigned* gM = (dir ? ATpk : Apk) + (size_t)m * (256*MQ);
    const uint4* gM4 = (const uint4*)gM;
    const size_t eb0 = ((size_t)(m*MB + b0))     * ML * MQ;
    const size_t eb1 = ((size_t)(m*MB + b0 + 1)) * ML * MQ;
    const float* Eb0 = E + eb0;
    const float* Eb1 = E + eb1;

    // ---- preload register stash (pairs 0..20) ----
    uint4 Ar[NREGP*4];
    #pragma unroll
    for (int p = 0; p < NREGP; ++p) {
        #pragma unroll
        for (int c = 0; c < 4; ++c)
            Ar[p*4+c] = gM4[(ig*32 + p)*128 + wj4 + c];
    }
    // ---- preload LDS slabs (pairs 21..23 for each ig) ----
    for (int k = tid; k < SLAB_ROWS*512; k += 256) {
        int row = k >> 9, j = k & 511;
        int P = (row/3)*32 + NREGP + (row%3);
        shm[row*SLAB_STR + j] = gM[(size_t)P*MQ + j];
    }
    __syncthreads();

    if (dir == 0) {
        // ================= forward =================
        float C0, C1;
        {   // t = 0
            float2 ip = *(const float2*)(initp + m*MQ + jown);
            float2 e0 = *(const float2*)(Eb0 + jown);
            float2 e1 = *(const float2*)(Eb1 + jown);
            float a00 = ip.x * e0.x, a01 = ip.y * e0.y;
            float a10 = ip.x * e1.x, a11 = ip.y * e1.y;
            float pc0 = a00 + a01, pc1 = a10 + a11;
            #pragma unroll
            for (int d = 1; d <= 32; d <<= 1) { pc0 += __shfl_xor(pc0, d); pc1 += __shfl_xor(pc1, d); }
            if (lane == 0) { shm[RBASE + w*2] = __float_as_uint(pc0);
                             shm[RBASE + w*2 + 1] = __float_as_uint(pc1); }
            __syncthreads();
            uint4 r0 = *(const uint4*)(shm + RBASE);
            uint4 r1 = *(const uint4*)(shm + RBASE + 4);
            float c0 = __uint_as_float(r0.x)+__uint_as_float(r0.z)+__uint_as_float(r1.x)+__uint_as_float(r1.z);
            float c1 = __uint_as_float(r0.y)+__uint_as_float(r0.w)+__uint_as_float(r1.y)+__uint_as_float(r1.w);
            float ic0 = 1.f/c0, ic1 = 1.f/c1;
            C0 = __logf(c0); C1 = __logf(c1);
            float n00 = a00*ic0, n01 = a01*ic0;
            float n10 = a10*ic1, n11 = a11*ic1;
            shm[ABASE + aown]       = PKU(n00, n01);
            shm[ABASE + ACH + aown] = PKU(n10, n11);
            float2 o0; o0.x = __logf(n00) + C0; o0.y = __logf(n01) + C0;
            float2 o1; o1.x = __logf(n10) + C1; o1.y = __logf(n11) + C1;
            *(float2*)(P1 + eb0 + jown) = o0;
            *(float2*)(P1 + eb1 + jown) = o1;
            __syncthreads();
        }
        #pragma unroll 1
        for (int t = 1; t < ML; ++t) {
            float2 e0 = *(const float2*)(Eb0 + (size_t)t*MQ + jown);
            float2 e1 = *(const float2*)(Eb1 + (size_t)t*MQ + jown);
            float mv00, mv01, mv10, mv11;
            MATVEC(mv00, mv01, mv10, mv11);
            float a00 = mv00 * e0.x, a01 = mv01 * e0.y;
            float a10 = mv10 * e1.x, a11 = mv11 * e1.y;
            float pc0 = a00 + a01, pc1 = a10 + a11;
            #pragma unroll
            for (int d = 1; d <= 32; d <<= 1) { pc0 += __shfl_xor(pc0, d); pc1 += __shfl_xor(pc1, d); }
            if (lane == 0) { shm[RBASE + w*2] = __float_as_uint(pc0);
                             shm[RBASE + w*2 + 1] = __float_as_uint(pc1); }
            __syncthreads();
            uint4 r0 = *(const uint4*)(shm + RBASE);
            uint4 r1 = *(const uint4*)(shm + RBASE + 4);
            float c0 = __uint_as_float(r0.x)+__uint_as_float(r0.z)+__uint_as_float(r1.x)+__uint_as_float(r1.z);
            float c1 = __uint_as_float(r0.y)+__uint_as_float(r0.w)+__uint_as_float(r1.y)+__uint_as_float(r1.w);
            float ic0 = 1.f/c0, ic1 = 1.f/c1;
            C0 += __logf(c0) - LOG16f;
            C1 += __logf(c1) - LOG16f;
            float n00 = a00*ic0, n01 = a01*ic0;
            float n10 = a10*ic1, n11 = a11*ic1;
            shm[ABASE + aown]       = PKU(n00, n01);
            shm[ABASE + ACH + aown] = PKU(n10, n11);
            float2 o0; o0.x = __logf(n00) + C0; o0.y = __logf(n01) + C0;
            float2 o1; o1.x = __logf(n10) + C1; o1.y = __logf(n11) + C1;
            *(float2*)(P1 + eb0 + (size_t)t*MQ + jown) = o0;
            *(float2*)(P1 + eb1 + (size_t)t*MQ + jown) = o1;
            __syncthreads();
        }
        if (tid == 0) {
            llws[m*MB + b0]     = C0;
            llws[m*MB + b0 + 1] = C1;
            out[NPOST + m*MB + b0]     = C0;
            out[NPOST + m*MB + b0 + 1] = C1;
        }
    } else {
        // ================= backward =================
        float D0 = 0.f, D1 = 0.f;
        {   // t = L-1: beta_hat = 1, P2 = 0, w-vec = E[L-1]*256
            float2 e0 = *(const float2*)(Eb0 + (size_t)(ML-1)*MQ + jown);
            float2 e1 = *(const float2*)(Eb1 + (size_t)(ML-1)*MQ + jown);
            shm[ABASE + aown]       = PKU(e0.x * 256.f, e0.y * 256.f);
            shm[ABASE + ACH + aown] = PKU(e1.x * 256.f, e1.y * 256.f);
            float2 z; z.x = 0.f; z.y = 0.f;
            *(float2*)(out + eb0 + (size_t)(ML-1)*MQ + jown) = z;
            *(float2*)(out + eb1 + (size_t)(ML-1)*MQ + jown) = z;
            __syncthreads();
        }
        #pragma unroll 1
        for (int t = ML-2; t >= 0; --t) {
            float2 e0 = *(const float2*)(Eb0 + (size_t)t*MQ + jown);
            float2 e1 = *(const float2*)(Eb1 + (size_t)t*MQ + jown);
            float mv00, mv01, mv10, mv11;
            MATVEC(mv00, mv01, mv10, mv11);
            float pc0 = mv00 + mv01, pc1 = mv10 + mv11;
            #pragma unroll
            for (int d = 1; d <= 32; d <<= 1) { pc0 += __shfl_xor(pc0, d); pc1 += __shfl_xor(pc1, d); }
            if (lane == 0) { shm[RBASE + w*2] = __float_as_uint(pc0);
                             shm[RBASE + w*2 + 1] = __float_as_uint(pc1); }
            __syncthreads();
            uint4 r0 = *(const uint4*)(shm + RBASE);
            uint4 r1 = *(const uint4*)(shm + RBASE + 4);
            float c0 = __uint_as_float(r0.x)+__uint_as_float(r0.z)+__uint_as_float(r1.x)+__uint_as_float(r1.z);
            float c1 = __uint_as_float(r0.y)+__uint_as_float(r0.w)+__uint_as_float(r1.y)+__uint_as_float(r1.w);
            float ic0 = 1.f/c0, ic1 = 1.f/c1;
            D0 += __logf(c0) - LOG4096f;
            D1 += __logf(c1) - LOG4096f;
            float n00 = mv00*ic0, n01 = mv01*ic0;
            float n10 = mv10*ic1, n11 = mv11*ic1;
            shm[ABASE + aown]       = PKU(n00 * e0.x * 256.f, n01 * e0.y * 256.f);
            shm[ABASE + ACH + aown] = PKU(n10 * e1.x * 256.f, n11 * e1.y * 256.f);
            float2 o0; o0.x = __logf(n00) + D0; o0.y = __logf(n01) + D0;
            float2 o1; o1.x = __logf(n10) + D1; o1.y = __logf(n11) + D1;
            *(float2*)(out + eb0 + (size_t)t*MQ + jown) = o0;
            *(float2*)(out + eb1 + (size_t)t*MQ + jown) = o1;
            __syncthreads();
        }
    }
}

// ---------------- combine: out = P2(out) + P1 - loglik ----------------
__global__ void k_combine(const float* __restrict__ P1, const float* __restrict__ llws,
                          float* __restrict__ out) {
    size_t idx = ((size_t)blockIdx.x * 256 + threadIdx.x) * 4;
    int mb = (int)(idx >> 18);                  // L*Q = 262144 per (m,b)
    float ll = llws[mb];
    float4 p = *(const float4*)(P1 + idx);
    float4 o = *(const float4*)(out + idx);
    o.x = o.x + p.x - ll;
    o.y = o.y + p.y - ll;
    o.z = o.z + p.z - ll;
    o.w = o.w + p.w - ll;
    *(float4*)(out + idx) = o;
}

extern "C" void kernel_launch(void* const* d_in, const int* in_sizes, int n_in,
                              void* d_out, int out_size, void* d_ws, size_t ws_size,
                              hipStream_t stream) {
    (void)in_sizes; (void)n_in; (void)out_size; (void)ws_size;
    const float* inp   = (const float*)d_in[0];
    const float* trans = (const float*)d_in[1];
    const float* emis  = (const float*)d_in[2];
    const float* initl = (const float*)d_in[3];
    float* out = (float*)d_out;
    float* ws  = (float*)d_ws;

    float*    wsA    = ws + OFF_A;
    unsigned* wsApk  = (unsigned*)(ws + OFF_APK);
    unsigned* wsATpk = (unsigned*)(ws + OFF_ATPK);
    float*    wsB    = ws + OFF_B;
    float*    wsInit = ws + OFF_INIT;
    float*    wsE    = ws + OFF_E;
    float*    wsP1   = ws + OFF_P1;
    float*    wsLL   = ws + OFF_LL;

    k_softmaxA<<<MM*MQ, 256, 0, stream>>>(trans, wsA);
    k_packA<<<dim3(256, MM), 512, 0, stream>>>(wsA, wsApk);
    k_transposePack<<<dim3(8, 8, MM), dim3(64, 4), 0, stream>>>(wsA, wsATpk);
    k_bprep<<<MM, 512, 0, stream>>>(emis, initl, wsB, wsInit);
    k_ekernel<<<dim3(ML/8, MB, MM), 512, 0, stream>>>(inp, wsB, wsE);
    k_fwdbwd<<<64, 256, 0, stream>>>(wsApk, wsATpk, wsE, wsInit, wsP1, out, wsLL);
    k_combine<<<NPOST/1024, 256, 0, stream>>>(wsP1, wsLL, out);
}

// Round 5
// 1149.019 us; speedup vs baseline: 2.9022x; 2.9022x over previous
//
#include <hip/hip_runtime.h>
#include <math.h>

#define MQ 512           // states q
#define ML 512           // sequence length L
#define MS 26            // symbols
#define MB 32            // batch
#define MM 2             // models
#define NPOST (MM*MB*ML*MQ)   // 16777216

// ws layout (floats)
#define OFF_A    0
#define OFF_APK  (OFF_A + MM*MQ*MQ)         // uint32: [m][256 pairs][512 j]
#define OFF_ATPK (OFF_APK + MM*256*MQ)
#define OFF_B    (OFF_ATPK + MM*256*MQ)
#define OFF_INIT (OFF_B + MM*MQ*MS)
#define OFF_E    (OFF_INIT + MM*MQ)
#define OFF_P1   (OFF_E + NPOST)
#define OFF_LL   (OFF_P1 + NPOST)

#define LOG16f   2.7725887222397811f
#define LOG4096f 8.3177661667193433f

typedef _Float16 halfx2 __attribute__((ext_vector_type(2)));

#define BCH(x) __builtin_bit_cast(halfx2, (unsigned)(x))

#if __has_builtin(__builtin_amdgcn_fdot2)
#define FDOT2(a,b,c) __builtin_amdgcn_fdot2((a),(b),(c),false)
#else
static __device__ __forceinline__ float FDOT2(halfx2 a, halfx2 b, float c){
  return fmaf((float)a.x,(float)b.x, fmaf((float)a.y,(float)b.y,c));
}
#endif

#if __has_builtin(__builtin_amdgcn_cvt_pkrtz)
#define PKU(x,y) __builtin_bit_cast(unsigned, __builtin_amdgcn_cvt_pkrtz((x),(y)))
#else
static __device__ __forceinline__ unsigned PKU(float x, float y){
  halfx2 r; r.x=(_Float16)x; r.y=(_Float16)y; return __builtin_bit_cast(unsigned, r);
}
#endif

// ---------------- row softmax of transition logits -> A (prob domain) ----------------
__global__ void k_softmaxA(const float* __restrict__ tl, float* __restrict__ A) {
    int row = blockIdx.x;                       // m*512 + i
    const float* x = tl + (size_t)row * MQ;
    float* y = A + (size_t)row * MQ;
    int tid = threadIdx.x;                      // 256 threads
    float v0 = x[tid], v1 = x[tid + 256];
    float mx = fmaxf(v0, v1);
    #pragma unroll
    for (int d = 32; d >= 1; d >>= 1) mx = fmaxf(mx, __shfl_xor(mx, d));
    __shared__ float sm[4], ss[4];
    int w = tid >> 6;
    if ((tid & 63) == 0) sm[w] = mx;
    __syncthreads();
    mx = fmaxf(fmaxf(sm[0], sm[1]), fmaxf(sm[2], sm[3]));
    float e0 = expf(v0 - mx), e1 = expf(v1 - mx);
    float s = e0 + e1;
    #pragma unroll
    for (int d = 32; d >= 1; d >>= 1) s += __shfl_xor(s, d);
    if ((tid & 63) == 0) ss[w] = s;
    __syncthreads();
    s = ss[0] + ss[1] + ss[2] + ss[3];
    float inv = 1.0f / s;
    y[tid] = e0 * inv;
    y[tid + 256] = e1 * inv;
}

// ---------------- pack A (prob fp32) -> fp16 pairs along i, scaled x16 ----------------
__global__ void k_packA(const float* __restrict__ A, unsigned* __restrict__ Apk) {
    int P = blockIdx.x, m = blockIdx.y, j = threadIdx.x;   // 512 threads
    const float* s = A + ((size_t)(m*MQ) + 2*P) * MQ;
    float x0 = s[j] * 16.f, x1 = s[MQ + j] * 16.f;
    halfx2 r; r.x = (_Float16)x0; r.y = (_Float16)x1;
    Apk[((size_t)m*256 + P) * MQ + j] = __builtin_bit_cast(unsigned, r);
}

// ---------------- transpose A and pack pairs along j (for backward), scaled x16 -------
__global__ void k_transposePack(const float* __restrict__ A, unsigned* __restrict__ ATpk) {
    __shared__ float tile[64][65];
    int m = blockIdx.z;
    int i0 = blockIdx.x * 64, j0 = blockIdx.y * 64;
    int tx = threadIdx.x, ty = threadIdx.y;     // (64,4)
    for (int r = ty; r < 64; r += 4)
        tile[r][tx] = A[((size_t)(m*MQ + i0 + r))*MQ + j0 + tx];
    __syncthreads();
    for (int rp = ty; rp < 32; rp += 4) {
        float x0 = tile[tx][2*rp]   * 16.f;
        float x1 = tile[tx][2*rp+1] * 16.f;
        halfx2 r; r.x = (_Float16)x0; r.y = (_Float16)x1;
        ATpk[((size_t)m*256 + (j0>>1) + rp) * MQ + i0 + tx] = __builtin_bit_cast(unsigned, r);
    }
}

// ---------------- emission softmax (B) + init softmax ----------------
__global__ void k_bprep(const float* __restrict__ emis, const float* __restrict__ initl,
                        float* __restrict__ Bmat, float* __restrict__ initp) {
    int m = blockIdx.x;
    int q = threadIdx.x;                        // 512 threads
    const float* er = emis + ((size_t)(m*MQ) + q) * MS;
    float tv[MS];
    float mx = -1e30f;
    #pragma unroll
    for (int s = 0; s < MS; s++) { tv[s] = er[s]; mx = fmaxf(mx, tv[s]); }
    float sum = 0.f;
    #pragma unroll
    for (int s = 0; s < MS; s++) { tv[s] = expf(tv[s] - mx); sum += tv[s]; }
    float inv = 1.f / sum;
    float* bo = Bmat + ((size_t)(m*MQ) + q) * MS;
    #pragma unroll
    for (int s = 0; s < MS; s++) bo[s] = tv[s] * inv;

    __shared__ float red2[8];
    float v = initl[m*MQ + q];
    float mx2 = v;
    #pragma unroll
    for (int d = 32; d >= 1; d >>= 1) mx2 = fmaxf(mx2, __shfl_xor(mx2, d));
    if ((q & 63) == 0) red2[q >> 6] = mx2;
    __syncthreads();
    mx2 = red2[0];
    #pragma unroll
    for (int k = 1; k < 8; k++) mx2 = fmaxf(mx2, red2[k]);
    float e = expf(v - mx2);
    float s2 = e;
    #pragma unroll
    for (int d = 32; d >= 1; d >>= 1) s2 += __shfl_xor(s2, d);
    __syncthreads();
    if ((q & 63) == 0) red2[q >> 6] = s2;
    __syncthreads();
    s2 = 0.f;
    #pragma unroll
    for (int k = 0; k < 8; k++) s2 += red2[k];
    initp[m*MQ + q] = e / s2;
}

// ---------------- E[m,b,l,q] = sum_s inputs[m,b,l,s]*B[m,q,s] + EPS ----------------
__global__ void k_ekernel(const float* __restrict__ inp, const float* __restrict__ Bmat,
                          float* __restrict__ E) {
    int lc = blockIdx.x, b = blockIdx.y, m = blockIdx.z;
    int tid = threadIdx.x;                      // 512
    __shared__ float Bl[MQ * MS];               // 53KB
    __shared__ float xl[8 * MS];
    for (int k = tid; k < MQ * MS; k += 512) Bl[k] = Bmat[(size_t)m * MQ * MS + k];
    int l0 = lc * 8;
    const float* xin = inp + (((size_t)(m*MB + b) * ML + l0) * MS);
    for (int k = tid; k < 8 * MS; k += 512) xl[k] = xin[k];
    __syncthreads();
    float* Eo = E + (((size_t)(m*MB + b) * ML + l0) * MQ);
    const float* br = Bl + tid * MS;
    for (int l = 0; l < 8; l++) {
        float acc = 1e-16f;
        const float* xr = xl + l * MS;
        #pragma unroll
        for (int s = 0; s < MS; s++) acc = fmaf(br[s], xr[s], acc);
        Eo[l * MQ + tid] = acc;
    }
}

// ---------------- fused fwd/bwd: 128 blocks (dir,m,b) x 512 threads, 1 chain ----------
// 8 waves; wave w owns j in [64w,64w+64); lane ig=lane>>3 covers i in [64ig,64ig+64)
// (32 pairs), jg=lane&7 covers j-octet jbase=64w+8jg. After 3 butterfly stages lane
// owns j = jbase+ig. A split per ig: pairs 0..19 in VGPRs (160 regs), 20..25 in
// dynamic LDS (100KB), 26..31 streamed from L2 (96KB/step, rotating 2-buffer).

#define NREGP 20
#define NSLAB 6
#define SLAB_ROWS 48           // s*8 + ig
#define SLAB_STR  524
#define ABASE (SLAB_ROWS*SLAB_STR)    // 25152
#define RBASE (ABASE + 288)           // 25440
#define SHM_DW (RBASE + 16)           // 25456 dwords = 101824 B

#define DOT8(X0, X1, AD) do { halfx2 _ah = BCH(AD);                           \
  u[0]=FDOT2(BCH((X0).x),_ah,u[0]); u[1]=FDOT2(BCH((X0).y),_ah,u[1]);         \
  u[2]=FDOT2(BCH((X0).z),_ah,u[2]); u[3]=FDOT2(BCH((X0).w),_ah,u[3]);         \
  u[4]=FDOT2(BCH((X1).x),_ah,u[4]); u[5]=FDOT2(BCH((X1).y),_ah,u[5]);         \
  u[6]=FDOT2(BCH((X1).z),_ah,u[6]); u[7]=FDOT2(BCH((X1).w),_ah,u[7]);         \
} while(0)

#define LOADSV(DST, PI) do {                                                  \
  DST[0] = gM4[((PI)*128) + wj4 + 0]; DST[1] = gM4[((PI)*128) + wj4 + 1];     \
} while(0)

#define SLABDOT(S, AD) do {                                                   \
  const unsigned* _sp = shm + ((S)*8+ig)*SLAB_STR + jbase;                    \
  uint4 _s0 = *(const uint4*)(_sp + 0);                                       \
  uint4 _s1 = *(const uint4*)(_sp + 4);                                       \
  DOT8(_s0, _s1, AD);                                                         \
} while(0)

#define AQC(p) ((p&3)==0?aq[(p)>>2].x:((p&3)==1?aq[(p)>>2].y:((p&3)==2?aq[(p)>>2].z:aq[(p)>>2].w)))

// matvec + reduce: MV = full column sum for j = jown
#define MATVEC(MV) do {                                                       \
  float u[8];                                                                 \
  _Pragma("unroll") for (int k=0;k<8;k++) u[k]=0.f;                           \
  const unsigned* al = shm + ABASE + ig*36;                                   \
  uint4 aq[8];                                                                \
  _Pragma("unroll") for (int q=0;q<8;q++) aq[q] = *(const uint4*)(al + 4*q);  \
  uint4 sb0[2], sb1[2];                                                       \
  LOADSV(sb0, ig*32+26); LOADSV(sb1, ig*32+27);                               \
  _Pragma("unroll")                                                           \
  for (int p=0;p<NREGP;++p){                                                  \
    DOT8(Ar[p*2+0], Ar[p*2+1], AQC(p));                                       \
    if (p==6){  DOT8(sb0[0], sb0[1], aq[6].z); LOADSV(sb0, ig*32+28); }       \
    if (p==9){  DOT8(sb1[0], sb1[1], aq[6].w); LOADSV(sb1, ig*32+29); }       \
    if (p==12){ DOT8(sb0[0], sb0[1], aq[7].x); LOADSV(sb0, ig*32+30); }       \
    if (p==15){ DOT8(sb1[0], sb1[1], aq[7].y); LOADSV(sb1, ig*32+31); }       \
  }                                                                           \
  SLABDOT(0, aq[5].x);                                                        \
  SLABDOT(1, aq[5].y);                                                        \
  DOT8(sb0[0], sb0[1], aq[7].z);                                              \
  SLABDOT(2, aq[5].z);                                                        \
  SLABDOT(3, aq[5].w);                                                        \
  DOT8(sb1[0], sb1[1], aq[7].w);                                              \
  SLABDOT(4, aq[6].x);                                                        \
  SLABDOT(5, aq[6].y);                                                        \
  float v4[4];                                                                \
  { const int h=(ig>>2)&1;                                                    \
    _Pragma("unroll") for (int k=0;k<4;k++){                                  \
      float mi = h?u[k+4]:u[k]; float ot = h?u[k]:u[k+4];                     \
      v4[k] = mi + __shfl_xor(ot,32); } }                                     \
  float v2[2];                                                                \
  { const int h=(ig>>1)&1;                                                    \
    _Pragma("unroll") for (int k=0;k<2;k++){                                  \
      float mi = h?v4[k+2]:v4[k]; float ot = h?v4[k]:v4[k+2];                 \
      v2[k] = mi + __shfl_xor(ot,16); } }                                     \
  { const int h=ig&1;                                                         \
    float mi = h?v2[1]:v2[0]; float ot = h?v2[0]:v2[1];                       \
    MV = mi + __shfl_xor(ot,8); }                                             \
} while(0)

__global__ __launch_bounds__(512, 2) void k_fwdbwd(
    const unsigned* __restrict__ Apk, const unsigned* __restrict__ ATpk,
    const float* __restrict__ E, const float* __restrict__ initp,
    float* __restrict__ P1, float* __restrict__ out, float* __restrict__ llws)
{
    extern __shared__ __align__(16) unsigned shm[];
    const int bid = blockIdx.x;                 // 128 blocks
    const int dir = bid & 1, m = (bid >> 1) & 1;
    const int b  = bid >> 2;                    // 0..31
    const int tid = threadIdx.x;
    const int w = tid >> 6, lane = tid & 63;
    const int ig = lane >> 3, jg = lane & 7;
    const int jbase = w*64 + jg*8;
    const int wj4 = jbase >> 2;
    const int jown = jbase + ig;
    const int Pown = jown >> 1;
    const int aown = (Pown >> 5)*36 + (Pown & 31);

    const unsigned* gM = (dir ? ATpk : Apk) + (size_t)m * (256*MQ);
    const uint4* gM4 = (const uint4*)gM;
    const size_t eb = ((size_t)(m*MB + b)) * ML * MQ;
    const float* Eb = E + eb;

    // ---- preload register stash (pairs 0..19 of this lane's ig) ----
    uint4 Ar[NREGP*2];
    #pragma unroll
    for (int p = 0; p < NREGP; ++p) {
        Ar[p*2+0] = gM4[(ig*32 + p)*128 + wj4 + 0];
        Ar[p*2+1] = gM4[(ig*32 + p)*128 + wj4 + 1];
    }
    // ---- preload LDS slabs (pairs 20..25 per ig; row = s*8 + ig) ----
    for (int k = tid; k < SLAB_ROWS*512; k += 512) {
        int row = k >> 9, j = k & 511;
        int s = row >> 3, igr = row & 7;
        shm[row*SLAB_STR + j] = gM[(size_t)(igr*32 + NREGP + s)*MQ + j];
    }
    __syncthreads();

    if (dir == 0) {
        // ================= forward =================
        float C;
        {   // t = 0
            float ev = Eb[jown];
            float a = initp[m*MQ + jown] * ev;
            float pc = a;
            #pragma unroll
            for (int d = 1; d <= 32; d <<= 1) pc += __shfl_xor(pc, d);
            if (lane == 0) shm[RBASE + w] = __float_as_uint(pc);
            __syncthreads();
            uint4 r0 = *(const uint4*)(shm + RBASE);
            uint4 r1 = *(const uint4*)(shm + RBASE + 4);
            float c = __uint_as_float(r0.x)+__uint_as_float(r0.y)+__uint_as_float(r0.z)+__uint_as_float(r0.w)
                    + __uint_as_float(r1.x)+__uint_as_float(r1.y)+__uint_as_float(r1.z)+__uint_as_float(r1.w);
            float ic = 1.f/c; C = __logf(c);
            float an = a * ic;
            float ap = __shfl_xor(an, 8);
            if (!(ig & 1)) shm[ABASE + aown] = PKU(an, ap);
            P1[eb + jown] = __logf(an) + C;
            __syncthreads();
        }
        #pragma unroll 1
        for (int t = 1; t < ML; ++t) {
            float ev = Eb[(size_t)t*MQ + jown];
            float mv;
            MATVEC(mv);
            float a = mv * ev;
            float pc = a;
            #pragma unroll
            for (int d = 1; d <= 32; d <<= 1) pc += __shfl_xor(pc, d);
            if (lane == 0) shm[RBASE + w] = __float_as_uint(pc);
            __syncthreads();
            uint4 r0 = *(const uint4*)(shm + RBASE);
            uint4 r1 = *(const uint4*)(shm + RBASE + 4);
            float c = __uint_as_float(r0.x)+__uint_as_float(r0.y)+__uint_as_float(r0.z)+__uint_as_float(r0.w)
                    + __uint_as_float(r1.x)+__uint_as_float(r1.y)+__uint_as_float(r1.z)+__uint_as_float(r1.w);
            float ic = 1.f/c; C += __logf(c) - LOG16f;
            float an = a * ic;
            float ap = __shfl_xor(an, 8);
            if (!(ig & 1)) shm[ABASE + aown] = PKU(an, ap);
            P1[eb + (size_t)t*MQ + jown] = __logf(an) + C;
            __syncthreads();
        }
        if (tid == 0) {
            llws[m*MB + b] = C;
            out[NPOST + m*MB + b] = C;
        }
    } else {
        // ================= backward =================
        float D = 0.f;
        {   // t = L-1: beta_hat = 1, P2 = 0, wl = E[L-1]*256
            float ev = Eb[(size_t)(ML-1)*MQ + jown];
            float wv = ev * 256.f;
            float wp = __shfl_xor(wv, 8);
            if (!(ig & 1)) shm[ABASE + aown] = PKU(wv, wp);
            out[eb + (size_t)(ML-1)*MQ + jown] = 0.f;
            __syncthreads();
        }
        #pragma unroll 1
        for (int t = ML-2; t >= 0; --t) {
            float ev = Eb[(size_t)t*MQ + jown];
            float mv;
            MATVEC(mv);
            float pc = mv;
            #pragma unroll
            for (int d = 1; d <= 32; d <<= 1) pc += __shfl_xor(pc, d);
            if (lane == 0) shm[RBASE + w] = __float_as_uint(pc);
            __syncthreads();
            uint4 r0 = *(const uint4*)(shm + RBASE);
            uint4 r1 = *(const uint4*)(shm + RBASE + 4);
            float c = __uint_as_float(r0.x)+__uint_as_float(r0.y)+__uint_as_float(r0.z)+__uint_as_float(r0.w)
                    + __uint_as_float(r1.x)+__uint_as_float(r1.y)+__uint_as_float(r1.z)+__uint_as_float(r1.w);
            float ic = 1.f/c; D += __logf(c) - LOG4096f;
            float bn = mv * ic;
            float wv = bn * ev * 256.f;
            float wp = __shfl_xor(wv, 8);
            if (!(ig & 1)) shm[ABASE + aown] = PKU(wv, wp);
            out[eb + (size_t)t*MQ + jown] = __logf(bn) + D;
            __syncthreads();
        }
    }
}

// ---------------- combine: out = P2(out) + P1 - loglik ----------------
__global__ void k_combine(const float* __restrict__ P1, const float* __restrict__ llws,
                          float* __restrict__ out) {
    size_t idx = ((size_t)blockIdx.x * 256 + threadIdx.x) * 4;
    int mb = (int)(idx >> 18);                  // L*Q = 262144 per (m,b)
    float ll = llws[mb];
    float4 p = *(const float4*)(P1 + idx);
    float4 o = *(const float4*)(out + idx);
    o.x = o.x + p.x - ll;
    o.y = o.y + p.y - ll;
    o.z = o.z + p.z - ll;
    o.w = o.w + p.w - ll;
    *(float4*)(out + idx) = o;
}

extern "C" void kernel_launch(void* const* d_in, const int* in_sizes, int n_in,
                              void* d_out, int out_size, void* d_ws, size_t ws_size,
                              hipStream_t stream) {
    (void)in_sizes; (void)n_in; (void)out_size; (void)ws_size;
    const float* inp   = (const float*)d_in[0];
    const float* trans = (const float*)d_in[1];
    const float* emis  = (const float*)d_in[2];
    const float* initl = (const float*)d_in[3];
    float* out = (float*)d_out;
    float* ws  = (float*)d_ws;

    float*    wsA    = ws + OFF_A;
    unsigned* wsApk  = (unsigned*)(ws + OFF_APK);
    unsigned* wsATpk = (unsigned*)(ws + OFF_ATPK);
    float*    wsB    = ws + OFF_B;
    float*    wsInit = ws + OFF_INIT;
    float*    wsE    = ws + OFF_E;
    float*    wsP1   = ws + OFF_P1;
    float*    wsLL   = ws + OFF_LL;

    // allow >64KB dynamic LDS (idempotent; safe under graph capture — not a stream op)
    (void)hipFuncSetAttribute((const void*)k_fwdbwd,
                              hipFuncAttributeMaxDynamicSharedMemorySize,
                              SHM_DW * 4);

    k_softmaxA<<<MM*MQ, 256, 0, stream>>>(trans, wsA);
    k_packA<<<dim3(256, MM), 512, 0, stream>>>(wsA, wsApk);
    k_transposePack<<<dim3(8, 8, MM), dim3(64, 4), 0, stream>>>(wsA, wsATpk);
    k_bprep<<<MM, 512, 0, stream>>>(emis, initl, wsB, wsInit);
    k_ekernel<<<dim3(ML/8, MB, MM), 512, 0, stream>>>(inp, wsB, wsE);
    k_fwdbwd<<<128, 512, SHM_DW * 4, stream>>>(wsApk, wsATpk, wsE, wsInit, wsP1, out, wsLL);
    k_combine<<<NPOST/1024, 256, 0, stream>>>(wsP1, wsLL, out);
}

// Round 6
// 1116.828 us; speedup vs baseline: 2.9858x; 1.0288x over previous
//
#include <hip/hip_runtime.h>
#include <math.h>

#define MQ 512           // states q
#define ML 512           // sequence length L
#define MS 26            // symbols
#define MB 32            // batch
#define MM 2             // models
#define NPOST (MM*MB*ML*MQ)   // 16777216

// ws layout (floats)
#define OFF_A    0
#define OFF_APK  (OFF_A + MM*MQ*MQ)         // uint32: [m][256 pairs][512 j]
#define OFF_ATPK (OFF_APK + MM*256*MQ)
#define OFF_B    (OFF_ATPK + MM*256*MQ)
#define OFF_INIT (OFF_B + MM*MQ*MS)
#define OFF_E    (OFF_INIT + MM*MQ)
#define OFF_P1   (OFF_E + NPOST)
#define OFF_LL   (OFF_P1 + NPOST)

#define LOG16f   2.7725887222397811f
#define LOG4096f 8.3177661667193433f

typedef _Float16 halfx2 __attribute__((ext_vector_type(2)));

#define BCH(x) __builtin_bit_cast(halfx2, (unsigned)(x))

#if __has_builtin(__builtin_amdgcn_fdot2)
#define FDOT2(a,b,c) __builtin_amdgcn_fdot2((a),(b),(c),false)
#else
static __device__ __forceinline__ float FDOT2(halfx2 a, halfx2 b, float c){
  return fmaf((float)a.x,(float)b.x, fmaf((float)a.y,(float)b.y,c));
}
#endif

#if __has_builtin(__builtin_amdgcn_cvt_pkrtz)
#define PKU(x,y) __builtin_bit_cast(unsigned, __builtin_amdgcn_cvt_pkrtz((x),(y)))
#else
static __device__ __forceinline__ unsigned PKU(float x, float y){
  halfx2 r; r.x=(_Float16)x; r.y=(_Float16)y; return __builtin_bit_cast(unsigned, r);
}
#endif

// ---------------- row softmax of transition logits -> A (prob domain) ----------------
__global__ void k_softmaxA(const float* __restrict__ tl, float* __restrict__ A) {
    int row = blockIdx.x;                       // m*512 + i
    const float* x = tl + (size_t)row * MQ;
    float* y = A + (size_t)row * MQ;
    int tid = threadIdx.x;                      // 256 threads
    float v0 = x[tid], v1 = x[tid + 256];
    float mx = fmaxf(v0, v1);
    #pragma unroll
    for (int d = 32; d >= 1; d >>= 1) mx = fmaxf(mx, __shfl_xor(mx, d));
    __shared__ float sm[4], ss[4];
    int w = tid >> 6;
    if ((tid & 63) == 0) sm[w] = mx;
    __syncthreads();
    mx = fmaxf(fmaxf(sm[0], sm[1]), fmaxf(sm[2], sm[3]));
    float e0 = expf(v0 - mx), e1 = expf(v1 - mx);
    float s = e0 + e1;
    #pragma unroll
    for (int d = 32; d >= 1; d >>= 1) s += __shfl_xor(s, d);
    if ((tid & 63) == 0) ss[w] = s;
    __syncthreads();
    s = ss[0] + ss[1] + ss[2] + ss[3];
    float inv = 1.0f / s;
    y[tid] = e0 * inv;
    y[tid + 256] = e1 * inv;
}

// ---------------- pack A (prob fp32) -> fp16 pairs along i, scaled x16 ----------------
__global__ void k_packA(const float* __restrict__ A, unsigned* __restrict__ Apk) {
    int P = blockIdx.x, m = blockIdx.y, j = threadIdx.x;   // 512 threads
    const float* s = A + ((size_t)(m*MQ) + 2*P) * MQ;
    float x0 = s[j] * 16.f, x1 = s[MQ + j] * 16.f;
    halfx2 r; r.x = (_Float16)x0; r.y = (_Float16)x1;
    Apk[((size_t)m*256 + P) * MQ + j] = __builtin_bit_cast(unsigned, r);
}

// ---------------- transpose A and pack pairs along j (for backward), scaled x16 -------
__global__ void k_transposePack(const float* __restrict__ A, unsigned* __restrict__ ATpk) {
    __shared__ float tile[64][65];
    int m = blockIdx.z;
    int i0 = blockIdx.x * 64, j0 = blockIdx.y * 64;
    int tx = threadIdx.x, ty = threadIdx.y;     // (64,4)
    for (int r = ty; r < 64; r += 4)
        tile[r][tx] = A[((size_t)(m*MQ + i0 + r))*MQ + j0 + tx];
    __syncthreads();
    for (int rp = ty; rp < 32; rp += 4) {
        float x0 = tile[tx][2*rp]   * 16.f;
        float x1 = tile[tx][2*rp+1] * 16.f;
        halfx2 r; r.x = (_Float16)x0; r.y = (_Float16)x1;
        ATpk[((size_t)m*256 + (j0>>1) + rp) * MQ + i0 + tx] = __builtin_bit_cast(unsigned, r);
    }
}

// ---------------- emission softmax (B) + init softmax ----------------
__global__ void k_bprep(const float* __restrict__ emis, const float* __restrict__ initl,
                        float* __restrict__ Bmat, float* __restrict__ initp) {
    int m = blockIdx.x;
    int q = threadIdx.x;                        // 512 threads
    const float* er = emis + ((size_t)(m*MQ) + q) * MS;
    float tv[MS];
    float mx = -1e30f;
    #pragma unroll
    for (int s = 0; s < MS; s++) { tv[s] = er[s]; mx = fmaxf(mx, tv[s]); }
    float sum = 0.f;
    #pragma unroll
    for (int s = 0; s < MS; s++) { tv[s] = expf(tv[s] - mx); sum += tv[s]; }
    float inv = 1.f / sum;
    float* bo = Bmat + ((size_t)(m*MQ) + q) * MS;
    #pragma unroll
    for (int s = 0; s < MS; s++) bo[s] = tv[s] * inv;

    __shared__ float red2[8];
    float v = initl[m*MQ + q];
    float mx2 = v;
    #pragma unroll
    for (int d = 32; d >= 1; d >>= 1) mx2 = fmaxf(mx2, __shfl_xor(mx2, d));
    if ((q & 63) == 0) red2[q >> 6] = mx2;
    __syncthreads();
    mx2 = red2[0];
    #pragma unroll
    for (int k = 1; k < 8; k++) mx2 = fmaxf(mx2, red2[k]);
    float e = expf(v - mx2);
    float s2 = e;
    #pragma unroll
    for (int d = 32; d >= 1; d >>= 1) s2 += __shfl_xor(s2, d);
    __syncthreads();
    if ((q & 63) == 0) red2[q >> 6] = s2;
    __syncthreads();
    s2 = 0.f;
    #pragma unroll
    for (int k = 0; k < 8; k++) s2 += red2[k];
    initp[m*MQ + q] = e / s2;
}

// ---------------- E[m,b,l,q] = sum_s inputs[m,b,l,s]*B[m,q,s] + EPS ----------------
__global__ void k_ekernel(const float* __restrict__ inp, const float* __restrict__ Bmat,
                          float* __restrict__ E) {
    int lc = blockIdx.x, b = blockIdx.y, m = blockIdx.z;
    int tid = threadIdx.x;                      // 512
    __shared__ float Bl[MQ * MS];               // 53KB
    __shared__ float xl[8 * MS];
    for (int k = tid; k < MQ * MS; k += 512) Bl[k] = Bmat[(size_t)m * MQ * MS + k];
    int l0 = lc * 8;
    const float* xin = inp + (((size_t)(m*MB + b) * ML + l0) * MS);
    for (int k = tid; k < 8 * MS; k += 512) xl[k] = xin[k];
    __syncthreads();
    float* Eo = E + (((size_t)(m*MB + b) * ML + l0) * MQ);
    const float* br = Bl + tid * MS;
    for (int l = 0; l < 8; l++) {
        float acc = 1e-16f;
        const float* xr = xl + l * MS;
        #pragma unroll
        for (int s = 0; s < MS; s++) acc = fmaf(br[s], xr[s], acc);
        Eo[l * MQ + tid] = acc;
    }
}

// ---------------- fused fwd/bwd: 128 blocks (dir,m,b) x 512 threads, 1 chain ----------
// 8 waves; wave w owns j in [64w,64w+64); lane ig=lane>>3 covers i in [64ig,64ig+64)
// (32 pairs), jg=lane&7 covers j-octet jbase=64w+8jg. After 3 butterfly stages lane
// owns j = jbase+ig. A split per ig: pairs 0..19 in VGPRs (160 regs), 20..27 in
// dynamic LDS (134KB), 28..31 streamed from L2 (64KB/step, loaded at step top,
// consumed at step bottom -> latency fully covered).

#define NREGP 20
#define NSLAB 8
#define SLAB_ROWS 64           // s*8 + ig
#define SLAB_STR  524
#define ABASE (SLAB_ROWS*SLAB_STR)    // 33536
#define RBASE (ABASE + 288)           // 33824
#define SHM_DW (RBASE + 16)           // 33840 dwords = 135360 B

#define DOT8(X0, X1, AD) do { halfx2 _ah = BCH(AD);                           \
  u[0]=FDOT2(BCH((X0).x),_ah,u[0]); u[1]=FDOT2(BCH((X0).y),_ah,u[1]);         \
  u[2]=FDOT2(BCH((X0).z),_ah,u[2]); u[3]=FDOT2(BCH((X0).w),_ah,u[3]);         \
  u[4]=FDOT2(BCH((X1).x),_ah,u[4]); u[5]=FDOT2(BCH((X1).y),_ah,u[5]);         \
  u[6]=FDOT2(BCH((X1).z),_ah,u[6]); u[7]=FDOT2(BCH((X1).w),_ah,u[7]);         \
} while(0)

#define LOADSV(DST, PI) do {                                                  \
  DST[0] = gM4[((PI)*128) + wj4 + 0]; DST[1] = gM4[((PI)*128) + wj4 + 1];     \
} while(0)

#define SLABDOT(S, AD) do {                                                   \
  const unsigned* _sp = shm + ((S)*8+ig)*SLAB_STR + jbase;                    \
  uint4 _s0 = *(const uint4*)(_sp + 0);                                       \
  uint4 _s1 = *(const uint4*)(_sp + 4);                                       \
  DOT8(_s0, _s1, AD);                                                         \
} while(0)

// matvec + reduce: MV = full column sum for j = jown.
// alpha dword map: p=0..19 -> reg pairs; 20..27 -> LDS slabs; 28..31 -> stream bufs.
#define MATVEC(MV) do {                                                       \
  float u[8];                                                                 \
  _Pragma("unroll") for (int k=0;k<8;k++) u[k]=0.f;                           \
  const unsigned* al = shm + ABASE + ig*36;                                   \
  uint4 sb0[2], sb1[2], sb2[2], sb3[2];                                       \
  LOADSV(sb0, ig*32+28); LOADSV(sb1, ig*32+29);                               \
  LOADSV(sb2, ig*32+30); LOADSV(sb3, ig*32+31);                               \
  uint4 aq0 = *(const uint4*)(al+0);                                          \
  uint4 aq1 = *(const uint4*)(al+4);                                          \
  uint4 aq2, aq3, aq4, aq5, aq6, aq7;                                         \
  _Pragma("unroll")                                                           \
  for (int p=0;p<NREGP;++p){                                                  \
    if (p==2)  aq2 = *(const uint4*)(al+8);                                   \
    if (p==6)  aq3 = *(const uint4*)(al+12);                                  \
    if (p==10) aq4 = *(const uint4*)(al+16);                                  \
    if (p==14) aq5 = *(const uint4*)(al+20);                                  \
    if (p==16) aq6 = *(const uint4*)(al+24);                                  \
    if (p==18) aq7 = *(const uint4*)(al+28);                                  \
    const uint4 qq = (p>>2)==0?aq0:((p>>2)==1?aq1:((p>>2)==2?aq2:((p>>2)==3?aq3:aq4))); \
    unsigned ad = ((p&3)==0)?qq.x:(((p&3)==1)?qq.y:(((p&3)==2)?qq.z:qq.w));   \
    DOT8(Ar[p*2+0], Ar[p*2+1], ad);                                           \
  }                                                                           \
  SLABDOT(0, aq5.x); SLABDOT(1, aq5.y);                                       \
  DOT8(sb0[0], sb0[1], aq7.x);                                                \
  SLABDOT(2, aq5.z); SLABDOT(3, aq5.w);                                       \
  DOT8(sb1[0], sb1[1], aq7.y);                                                \
  SLABDOT(4, aq6.x); SLABDOT(5, aq6.y);                                       \
  DOT8(sb2[0], sb2[1], aq7.z);                                                \
  SLABDOT(6, aq6.z); SLABDOT(7, aq6.w);                                       \
  DOT8(sb3[0], sb3[1], aq7.w);                                                \
  float v4[4];                                                                \
  { const int h=(ig>>2)&1;                                                    \
    _Pragma("unroll") for (int k=0;k<4;k++){                                  \
      float mi = h?u[k+4]:u[k]; float ot = h?u[k]:u[k+4];                     \
      v4[k] = mi + __shfl_xor(ot,32); } }                                     \
  float v2[2];                                                                \
  { const int h=(ig>>1)&1;                                                    \
    _Pragma("unroll") for (int k=0;k<2;k++){                                  \
      float mi = h?v4[k+2]:v4[k]; float ot = h?v4[k]:v4[k+2];                 \
      v2[k] = mi + __shfl_xor(ot,16); } }                                     \
  { const int h=ig&1;                                                         \
    float mi = h?v2[1]:v2[0]; float ot = h?v2[0]:v2[1];                       \
    MV = mi + __shfl_xor(ot,8); }                                             \
} while(0)

__global__ __launch_bounds__(512, 2) void k_fwdbwd(
    const unsigned* __restrict__ Apk, const unsigned* __restrict__ ATpk,
    const float* __restrict__ E, const float* __restrict__ initp,
    float* __restrict__ P1, float* __restrict__ out, float* __restrict__ llws)
{
    extern __shared__ __align__(16) unsigned shm[];
    const int bid = blockIdx.x;                 // 128 blocks
    const int dir = bid & 1, m = (bid >> 1) & 1;
    const int b  = bid >> 2;                    // 0..31
    const int tid = threadIdx.x;
    const int w = tid >> 6, lane = tid & 63;
    const int ig = lane >> 3, jg = lane & 7;
    const int jbase = w*64 + jg*8;
    const int wj4 = jbase >> 2;
    const int jown = jbase + ig;
    const int Pown = jown >> 1;
    const int aown = (Pown >> 5)*36 + (Pown & 31);

    const unsigned* gM = (dir ? ATpk : Apk) + (size_t)m * (256*MQ);
    const uint4* gM4 = (const uint4*)gM;
    const size_t eb = ((size_t)(m*MB + b)) * ML * MQ;
    const float* Eb = E + eb;

    // ---- preload register stash (pairs 0..19 of this lane's ig) ----
    uint4 Ar[NREGP*2];
    #pragma unroll
    for (int p = 0; p < NREGP; ++p) {
        Ar[p*2+0] = gM4[(ig*32 + p)*128 + wj4 + 0];
        Ar[p*2+1] = gM4[(ig*32 + p)*128 + wj4 + 1];
    }
    // ---- preload LDS slabs (pairs 20..27 per ig; row = s*8 + ig) ----
    for (int k = tid; k < SLAB_ROWS*512; k += 512) {
        int row = k >> 9, j = k & 511;
        int s = row >> 3, igr = row & 7;
        shm[row*SLAB_STR + j] = gM[(size_t)(igr*32 + NREGP + s)*MQ + j];
    }
    __syncthreads();

    if (dir == 0) {
        // ================= forward =================
        float C;
        {   // t = 0
            float ev = Eb[jown];
            float a = initp[m*MQ + jown] * ev;
            float pc = a;
            #pragma unroll
            for (int d = 1; d <= 32; d <<= 1) pc += __shfl_xor(pc, d);
            if (lane == 0) shm[RBASE + w] = __float_as_uint(pc);
            __syncthreads();
            uint4 r0 = *(const uint4*)(shm + RBASE);
            uint4 r1 = *(const uint4*)(shm + RBASE + 4);
            float c = __uint_as_float(r0.x)+__uint_as_float(r0.y)+__uint_as_float(r0.z)+__uint_as_float(r0.w)
                    + __uint_as_float(r1.x)+__uint_as_float(r1.y)+__uint_as_float(r1.z)+__uint_as_float(r1.w);
            float ic = 1.f/c; C = __logf(c);
            float an = a * ic;
            float ap = __shfl_xor(an, 8);
            if (!(ig & 1)) shm[ABASE + aown] = PKU(an, ap);
            P1[eb + jown] = __logf(an) + C;
            __syncthreads();
        }
        #pragma unroll 1
        for (int t = 1; t < ML; ++t) {
            float ev = Eb[(size_t)t*MQ + jown];
            float mv;
            MATVEC(mv);
            float a = mv * ev;
            float pc = a;
            #pragma unroll
            for (int d = 1; d <= 32; d <<= 1) pc += __shfl_xor(pc, d);
            if (lane == 0) shm[RBASE + w] = __float_as_uint(pc);
            __syncthreads();
            uint4 r0 = *(const uint4*)(shm + RBASE);
            uint4 r1 = *(const uint4*)(shm + RBASE + 4);
            float c = __uint_as_float(r0.x)+__uint_as_float(r0.y)+__uint_as_float(r0.z)+__uint_as_float(r0.w)
                    + __uint_as_float(r1.x)+__uint_as_float(r1.y)+__uint_as_float(r1.z)+__uint_as_float(r1.w);
            float ic = 1.f/c; C += __logf(c) - LOG16f;
            float an = a * ic;
            float ap = __shfl_xor(an, 8);
            if (!(ig & 1)) shm[ABASE + aown] = PKU(an, ap);
            P1[eb + (size_t)t*MQ + jown] = __logf(an) + C;
            __syncthreads();
        }
        if (tid == 0) {
            llws[m*MB + b] = C;
            out[NPOST + m*MB + b] = C;
        }
    } else {
        // ================= backward =================
        float D = 0.f;
        {   // t = L-1: beta_hat = 1, P2 = 0, wl = E[L-1]*256
            float ev = Eb[(size_t)(ML-1)*MQ + jown];
            float wv = ev * 256.f;
            float wp = __shfl_xor(wv, 8);
            if (!(ig & 1)) shm[ABASE + aown] = PKU(wv, wp);
            out[eb + (size_t)(ML-1)*MQ + jown] = 0.f;
            __syncthreads();
        }
        #pragma unroll 1
        for (int t = ML-2; t >= 0; --t) {
            float ev = Eb[(size_t)t*MQ + jown];
            float mv;
            MATVEC(mv);
            float pc = mv;
            #pragma unroll
            for (int d = 1; d <= 32; d <<= 1) pc += __shfl_xor(pc, d);
            if (lane == 0) shm[RBASE + w] = __float_as_uint(pc);
            __syncthreads();
            uint4 r0 = *(const uint4*)(shm + RBASE);
            uint4 r1 = *(const uint4*)(shm + RBASE + 4);
            float c = __uint_as_float(r0.x)+__uint_as_float(r0.y)+__uint_as_float(r0.z)+__uint_as_float(r0.w)
                    + __uint_as_float(r1.x)+__uint_as_float(r1.y)+__uint_as_float(r1.z)+__uint_as_float(r1.w);
            float ic = 1.f/c; D += __logf(c) - LOG4096f;
            float bn = mv * ic;
            float wv = bn * ev * 256.f;
            float wp = __shfl_xor(wv, 8);
            if (!(ig & 1)) shm[ABASE + aown] = PKU(wv, wp);
            out[eb + (size_t)t*MQ + jown] = __logf(bn) + D;
            __syncthreads();
        }
    }
}

// ---------------- combine: out = P2(out) + P1 - loglik ----------------
__global__ void k_combine(const float* __restrict__ P1, const float* __restrict__ llws,
                          float* __restrict__ out) {
    size_t idx = ((size_t)blockIdx.x * 256 + threadIdx.x) * 4;
    int mb = (int)(idx >> 18);                  // L*Q = 262144 per (m,b)
    float ll = llws[mb];
    float4 p = *(const float4*)(P1 + idx);
    float4 o = *(const float4*)(out + idx);
    o.x = o.x + p.x - ll;
    o.y = o.y + p.y - ll;
    o.z = o.z + p.z - ll;
    o.w = o.w + p.w - ll;
    *(float4*)(out + idx) = o;
}

extern "C" void kernel_launch(void* const* d_in, const int* in_sizes, int n_in,
                              void* d_out, int out_size, void* d_ws, size_t ws_size,
                              hipStream_t stream) {
    (void)in_sizes; (void)n_in; (void)out_size; (void)ws_size;
    const float* inp   = (const float*)d_in[0];
    const float* trans = (const float*)d_in[1];
    const float* emis  = (const float*)d_in[2];
    const float* initl = (const float*)d_in[3];
    float* out = (float*)d_out;
    float* ws  = (float*)d_ws;

    float*    wsA    = ws + OFF_A;
    unsigned* wsApk  = (unsigned*)(ws + OFF_APK);
    unsigned* wsATpk = (unsigned*)(ws + OFF_ATPK);
    float*    wsB    = ws + OFF_B;
    float*    wsInit = ws + OFF_INIT;
    float*    wsE    = ws + OFF_E;
    float*    wsP1   = ws + OFF_P1;
    float*    wsLL   = ws + OFF_LL;

    // allow >64KB dynamic LDS (idempotent; safe under graph capture — not a stream op)
    (void)hipFuncSetAttribute((const void*)k_fwdbwd,
                              hipFuncAttributeMaxDynamicSharedMemorySize,
                              SHM_DW * 4);

    k_softmaxA<<<MM*MQ, 256, 0, stream>>>(trans, wsA);
    k_packA<<<dim3(256, MM), 512, 0, stream>>>(wsA, wsApk);
    k_transposePack<<<dim3(8, 8, MM), dim3(64, 4), 0, stream>>>(wsA, wsATpk);
    k_bprep<<<MM, 512, 0, stream>>>(emis, initl, wsB, wsInit);
    k_ekernel<<<dim3(ML/8, MB, MM), 512, 0, stream>>>(inp, wsB, wsE);
    k_fwdbwd<<<128, 512, SHM_DW * 4, stream>>>(wsApk, wsATpk, wsE, wsInit, wsP1, out, wsLL);
    k_combine<<<NPOST/1024, 256, 0, stream>>>(wsP1, wsLL, out);
}

// Round 7
// 840.470 us; speedup vs baseline: 3.9676x; 1.3288x over previous
//
#include <hip/hip_runtime.h>
#include <math.h>

#define MQ 512           // states q
#define ML 512           // sequence length L
#define MS 26            // symbols
#define MB 32            // batch
#define MM 2             // models
#define NPOST (MM*MB*ML*MQ)   // 16777216

// ws layout (float slots)
#define OFF_A    0                               // MM*MQ*MQ fp32 prob A
#define OFF_AQ8  (OFF_A + MM*MQ*MQ)              // i8-packed A  [m][128 ip][512 j] dwords
#define OFF_ATQ8 (OFF_AQ8 + MM*128*MQ)           // i8-packed AT
#define OFF_CP   (OFF_ATQ8 + MM*128*MQ)          // col partial maxes [m][16][512]
#define OFF_ROWM (OFF_CP + MM*16*MQ)             // row maxes [m][512]
#define OFF_SCA  (OFF_ROWM + MM*MQ)              // 127/colmax
#define OFF_INVA (OFF_SCA + MM*MQ)               // colmax/127
#define OFF_SCT  (OFF_INVA + MM*MQ)              // 127/rowmax
#define OFF_INVT (OFF_SCT + MM*MQ)               // rowmax/127
#define OFF_B    (OFF_INVT + MM*MQ)
#define OFF_INIT (OFF_B + MM*MQ*MS)
#define OFF_E    (OFF_INIT + MM*MQ)
#define OFF_P1   (OFF_E + NPOST)
#define OFF_LL   (OFF_P1 + NPOST)

#if __has_builtin(__builtin_amdgcn_sdot4)
#define SDOT4(a,b,c) __builtin_amdgcn_sdot4((int)(a),(int)(b),(c),false)
#else
static __device__ __forceinline__ int SDOT4(unsigned a, unsigned b, int c){
  #pragma unroll
  for (int k=0;k<4;++k){
    int av = (int)((a >> (8*k)) & 0xffu); av = (av<<24)>>24;
    int bv = (int)((b >> (8*k)) & 0xffu); bv = (bv<<24)>>24;
    c += av*bv;
  }
  return c;
}
#endif

// ---------------- row softmax of transition logits -> A (prob domain) ----------------
__global__ void k_softmaxA(const float* __restrict__ tl, float* __restrict__ A) {
    int row = blockIdx.x;                       // m*512 + i
    const float* x = tl + (size_t)row * MQ;
    float* y = A + (size_t)row * MQ;
    int tid = threadIdx.x;                      // 256 threads
    float v0 = x[tid], v1 = x[tid + 256];
    float mx = fmaxf(v0, v1);
    #pragma unroll
    for (int d = 32; d >= 1; d >>= 1) mx = fmaxf(mx, __shfl_xor(mx, d));
    __shared__ float sm[4], ss[4];
    int w = tid >> 6;
    if ((tid & 63) == 0) sm[w] = mx;
    __syncthreads();
    mx = fmaxf(fmaxf(sm[0], sm[1]), fmaxf(sm[2], sm[3]));
    float e0 = expf(v0 - mx), e1 = expf(v1 - mx);
    float s = e0 + e1;
    #pragma unroll
    for (int d = 32; d >= 1; d >>= 1) s += __shfl_xor(s, d);
    if ((tid & 63) == 0) ss[w] = s;
    __syncthreads();
    s = ss[0] + ss[1] + ss[2] + ss[3];
    float inv = 1.0f / s;
    y[tid] = e0 * inv;
    y[tid + 256] = e1 * inv;
}

// ---------------- column partial maxes + row maxes of A ----------------
__global__ void k_amaxc(const float* __restrict__ A, float* __restrict__ colpart,
                        float* __restrict__ rowmax) {
    int g = blockIdx.x, m = blockIdx.y;         // 16 x MM
    int tid = threadIdx.x;                      // 512
    const float* Am = A + (size_t)m*MQ*MQ;
    float cm = 0.f;
    for (int r = 0; r < 32; ++r)
        cm = fmaxf(cm, Am[(size_t)(g*32+r)*MQ + tid]);
    colpart[((size_t)m*16 + g)*MQ + tid] = cm;
    int w = tid >> 6, lane = tid & 63;
    for (int k = 0; k < 4; ++k) {
        int row = g*32 + w*4 + k;
        const float* rp = Am + (size_t)row*MQ;
        float rm = 0.f;
        #pragma unroll
        for (int c = 0; c < 8; ++c) rm = fmaxf(rm, rp[lane + 64*c]);
        #pragma unroll
        for (int d = 1; d <= 32; d <<= 1) rm = fmaxf(rm, __shfl_xor(rm, d));
        if (lane == 0) rowmax[m*MQ + row] = rm;
    }
}

// ---------------- finalize scales ----------------
__global__ void k_amaxr(const float* __restrict__ colpart, const float* __restrict__ rowmax,
                        float* __restrict__ scA, float* __restrict__ invA,
                        float* __restrict__ scT, float* __restrict__ invT) {
    int m = blockIdx.x, j = threadIdx.x;        // MM x 512
    float cm = 0.f;
    #pragma unroll
    for (int g = 0; g < 16; ++g) cm = fmaxf(cm, colpart[((size_t)m*16 + g)*MQ + j]);
    scA[m*MQ + j] = 127.f / cm;  invA[m*MQ + j] = cm * (1.f/127.f);
    float rm = rowmax[m*MQ + j];
    scT[m*MQ + j] = 127.f / rm;  invT[m*MQ + j] = rm * (1.f/127.f);
}

// ---------------- pack A -> i8 dwords [m][ip][j], per-column scale ----------------
__global__ void k_packA8(const float* __restrict__ A, const float* __restrict__ sc,
                         unsigned* __restrict__ Aq) {
    int ip = blockIdx.x, m = blockIdx.y, j = threadIdx.x;  // 128 x MM, 512 thr
    const float* Am = A + (size_t)m*MQ*MQ;
    float s = sc[m*MQ + j];
    unsigned d = 0;
    #pragma unroll
    for (int r = 0; r < 4; ++r) {
        int q = (int)(Am[(size_t)(4*ip+r)*MQ + j] * s + 0.5f);
        d |= ((unsigned)q & 0xffu) << (8*r);
    }
    Aq[((size_t)m*128 + ip)*MQ + j] = d;
}

// ---------------- pack AT -> i8 dwords via 64x64 tile, per-row-of-A scale ----------
__global__ void k_packAT8(const float* __restrict__ A, const float* __restrict__ scT,
                          unsigned* __restrict__ ATq) {
    __shared__ float tile[64][65];
    int ipb = blockIdx.x, jjb = blockIdx.y, m = blockIdx.z;  // 8 x 8 x MM
    int tx = threadIdx.x, ty = threadIdx.y;     // (64,4)
    const float* Am = A + (size_t)m*MQ*MQ;
    for (int r = ty; r < 64; r += 4)
        tile[r][tx] = Am[(size_t)(jjb*64 + r)*MQ + ipb*64 + tx];
    __syncthreads();
    float s = scT[m*MQ + jjb*64 + tx];
    for (int ipl = ty; ipl < 16; ipl += 4) {
        unsigned d = 0;
        #pragma unroll
        for (int r = 0; r < 4; ++r) {
            int q = (int)(tile[tx][4*ipl + r] * s + 0.5f);
            d |= ((unsigned)q & 0xffu) << (8*r);
        }
        ATq[((size_t)m*128 + ipb*16 + ipl)*MQ + jjb*64 + tx] = d;
    }
}

// ---------------- emission softmax (B) + init softmax ----------------
__global__ void k_bprep(const float* __restrict__ emis, const float* __restrict__ initl,
                        float* __restrict__ Bmat, float* __restrict__ initp) {
    int m = blockIdx.x;
    int q = threadIdx.x;                        // 512 threads
    const float* er = emis + ((size_t)(m*MQ) + q) * MS;
    float tv[MS];
    float mx = -1e30f;
    #pragma unroll
    for (int s = 0; s < MS; s++) { tv[s] = er[s]; mx = fmaxf(mx, tv[s]); }
    float sum = 0.f;
    #pragma unroll
    for (int s = 0; s < MS; s++) { tv[s] = expf(tv[s] - mx); sum += tv[s]; }
    float inv = 1.f / sum;
    float* bo = Bmat + ((size_t)(m*MQ) + q) * MS;
    #pragma unroll
    for (int s = 0; s < MS; s++) bo[s] = tv[s] * inv;

    __shared__ float red2[8];
    float v = initl[m*MQ + q];
    float mx2 = v;
    #pragma unroll
    for (int d = 32; d >= 1; d >>= 1) mx2 = fmaxf(mx2, __shfl_xor(mx2, d));
    if ((q & 63) == 0) red2[q >> 6] = mx2;
    __syncthreads();
    mx2 = red2[0];
    #pragma unroll
    for (int k = 1; k < 8; k++) mx2 = fmaxf(mx2, red2[k]);
    float e = expf(v - mx2);
    float s2 = e;
    #pragma unroll
    for (int d = 32; d >= 1; d >>= 1) s2 += __shfl_xor(s2, d);
    __syncthreads();
    if ((q & 63) == 0) red2[q >> 6] = s2;
    __syncthreads();
    s2 = 0.f;
    #pragma unroll
    for (int k = 0; k < 8; k++) s2 += red2[k];
    initp[m*MQ + q] = e / s2;
}

// ---------------- E[m,b,l,q] = sum_s inputs[m,b,l,s]*B[m,q,s] + EPS ----------------
__global__ void k_ekernel(const float* __restrict__ inp, const float* __restrict__ Bmat,
                          float* __restrict__ E) {
    int lc = blockIdx.x, b = blockIdx.y, m = blockIdx.z;
    int tid = threadIdx.x;                      // 512
    __shared__ float Bl[MQ * MS];               // 53KB
    __shared__ float xl[8 * MS];
    for (int k = tid; k < MQ * MS; k += 512) Bl[k] = Bmat[(size_t)m * MQ * MS + k];
    int l0 = lc * 8;
    const float* xin = inp + (((size_t)(m*MB + b) * ML + l0) * MS);
    for (int k = tid; k < 8 * MS; k += 512) xl[k] = xin[k];
    __syncthreads();
    float* Eo = E + (((size_t)(m*MB + b) * ML + l0) * MQ);
    const float* br = Bl + tid * MS;
    for (int l = 0; l < 8; l++) {
        float acc = 1e-16f;
        const float* xr = xl + l * MS;
        #pragma unroll
        for (int s = 0; s < MS; s++) acc = fmaf(br[s], xr[s], acc);
        Eo[l * MQ + tid] = acc;
    }
}

// ---------------- fused fwd/bwd: 128 blocks (dir,m,b) x 512 threads, i8 dots ---------
// Whole A-slice in VGPRs: per lane 64 i x 8 j i8 = 32 uint4 = 128 regs. Alpha i8 in
// LDS (80 B per ig-slot -> conflict-free b128 broadcasts). Exact per-step fp32
// normalization; per-step exact max for quantization scale (piggybacked on the
// sum reduce). No slabs, no streaming.

#define RBASE 160                   // alpha bytes occupy dwords 0..159
#define SHM_DYN 81920               // request big dyn-LDS to pin 1 block/CU

#define DOTQ(P, AD) { u[0]=SDOT4(Ar[(P)*2+0].x,(AD),u[0]); u[1]=SDOT4(Ar[(P)*2+0].y,(AD),u[1]); \
  u[2]=SDOT4(Ar[(P)*2+0].z,(AD),u[2]); u[3]=SDOT4(Ar[(P)*2+0].w,(AD),u[3]);                     \
  u[4]=SDOT4(Ar[(P)*2+1].x,(AD),u[4]); u[5]=SDOT4(Ar[(P)*2+1].y,(AD),u[5]);                     \
  u[6]=SDOT4(Ar[(P)*2+1].z,(AD),u[6]); u[7]=SDOT4(Ar[(P)*2+1].w,(AD),u[7]); }

// matvec + ig-butterfly: MVI = i32 column sum for j = jown
#define MATVEC_I8(MVI) do {                                                   \
  int u[8];                                                                   \
  _Pragma("unroll") for (int k=0;k<8;k++) u[k]=0;                             \
  const uint4* av4 = (const uint4*)(shm + ig*20);                             \
  uint4 av0 = av4[0], av1 = av4[1], av2 = av4[2], av3 = av4[3];               \
  DOTQ(0,  av0.x) DOTQ(1,  av0.y) DOTQ(2,  av0.z) DOTQ(3,  av0.w)             \
  DOTQ(4,  av1.x) DOTQ(5,  av1.y) DOTQ(6,  av1.z) DOTQ(7,  av1.w)             \
  DOTQ(8,  av2.x) DOTQ(9,  av2.y) DOTQ(10, av2.z) DOTQ(11, av2.w)             \
  DOTQ(12, av3.x) DOTQ(13, av3.y) DOTQ(14, av3.z) DOTQ(15, av3.w)             \
  int v4[4];                                                                  \
  { const int h=(ig>>2)&1;                                                    \
    _Pragma("unroll") for (int k=0;k<4;k++){                                  \
      int mi = h?u[k+4]:u[k]; int ot = h?u[k]:u[k+4];                         \
      v4[k] = mi + __shfl_xor(ot,32); } }                                     \
  int v2[2];                                                                  \
  { const int h=(ig>>1)&1;                                                    \
    _Pragma("unroll") for (int k=0;k<2;k++){                                  \
      int mi = h?v4[k+2]:v4[k]; int ot = h?v4[k]:v4[k+2];                     \
      v2[k] = mi + __shfl_xor(ot,16); } }                                     \
  { const int h=ig&1;                                                         \
    int mi = h?v2[1]:v2[0]; int ot = h?v2[0]:v2[1];                           \
    MVI = mi + __shfl_xor(ot,8); }                                            \
} while(0)

// block reduce of (sum x, max y) -> c, mx   (uses RBASE, 2 dwords per wave)
#define BLOCKRED(X, Y, C, MX) do {                                            \
  float pc = (X), pm = (Y);                                                   \
  _Pragma("unroll")                                                           \
  for (int d = 1; d <= 32; d <<= 1) {                                         \
    pc += __shfl_xor(pc, d);                                                  \
    pm = fmaxf(pm, __shfl_xor(pm, d));                                        \
  }                                                                           \
  if (lane == 0) { shm[RBASE + w*2] = __float_as_uint(pc);                    \
                   shm[RBASE + w*2 + 1] = __float_as_uint(pm); }              \
  __syncthreads();                                                            \
  uint4 r0 = *(const uint4*)(shm + RBASE);                                    \
  uint4 r1 = *(const uint4*)(shm + RBASE + 4);                                \
  uint4 r2 = *(const uint4*)(shm + RBASE + 8);                                \
  uint4 r3 = *(const uint4*)(shm + RBASE + 12);                               \
  C = __uint_as_float(r0.x)+__uint_as_float(r0.z)+__uint_as_float(r1.x)+__uint_as_float(r1.z) \
    + __uint_as_float(r2.x)+__uint_as_float(r2.z)+__uint_as_float(r3.x)+__uint_as_float(r3.z);\
  MX = fmaxf(fmaxf(fmaxf(__uint_as_float(r0.y),__uint_as_float(r0.w)),                        \
                   fmaxf(__uint_as_float(r1.y),__uint_as_float(r1.w))),                       \
             fmaxf(fmaxf(__uint_as_float(r2.y),__uint_as_float(r2.w)),                        \
                   fmaxf(__uint_as_float(r3.y),__uint_as_float(r3.w))));                      \
} while(0)

__global__ __launch_bounds__(512, 2) void k_fwdbwd(
    const unsigned* __restrict__ Aq8, const unsigned* __restrict__ ATq8,
    const float* __restrict__ invA, const float* __restrict__ invT,
    const float* __restrict__ E, const float* __restrict__ initp,
    float* __restrict__ P1, float* __restrict__ out, float* __restrict__ llws)
{
    extern __shared__ __align__(16) unsigned shm[];
    const int bid = blockIdx.x;                 // 128 blocks
    const int dir = bid & 1, m = (bid >> 1) & 1;
    const int b  = bid >> 2;                    // 0..31
    const int tid = threadIdx.x;
    const int w = tid >> 6, lane = tid & 63;
    const int ig = lane >> 3, jg = lane & 7;
    const int jbase = w*64 + jg*8;
    const int jown = jbase + ig;

    const unsigned* gQ = (dir ? ATq8 : Aq8) + (size_t)m * (128*MQ);
    const uint4* gQ4 = (const uint4*)gQ;
    const float rsj = (dir ? invT : invA)[m*MQ + jown];
    const size_t eb = ((size_t)(m*MB + b)) * ML * MQ;
    const float* Eb = E + eb;

    // ---- preload i8 A-slice: 32 uint4 = 128 VGPRs ----
    uint4 Ar[32];
    #pragma unroll
    for (int p = 0; p < 16; ++p) {
        Ar[p*2+0] = gQ4[(size_t)(ig*16 + p)*128 + (jbase>>2)];
        Ar[p*2+1] = gQ4[(size_t)(ig*16 + p)*128 + (jbase>>2) + 1];
    }

    float inv_sa;                               // alpha dequant scale (max/126)
    unsigned char* ab = (unsigned char*)shm;
    const int wslot = (jown>>6)*80 + (jown&63); // byte addr of this lane's alpha slot

    if (dir == 0) {
        // ================= forward =================
        float C;
        {   // t = 0
            float ev = Eb[jown];
            float a = initp[m*MQ + jown] * ev;
            float c, mx;
            BLOCKRED(a, a, c, mx);
            float ic = 1.f/c; C = __logf(c);
            float an = a * ic, anmax = mx * ic;
            float qs = 126.f / anmax; inv_sa = anmax * (1.f/126.f);
            ab[wslot] = (unsigned char)(int)(an * qs + 0.5f);
            P1[eb + jown] = __logf(an) + C;
            __syncthreads();
        }
        #pragma unroll 1
        for (int t = 1; t < ML; ++t) {
            float ev = Eb[(size_t)t*MQ + jown];
            int mvi;
            MATVEC_I8(mvi);
            float mv = (float)mvi * (rsj * inv_sa);
            float a = mv * ev;
            float c, mx;
            BLOCKRED(a, a, c, mx);
            float ic = 1.f/c; C += __logf(c);
            float an = a * ic, anmax = mx * ic;
            float qs = 126.f / anmax; inv_sa = anmax * (1.f/126.f);
            ab[wslot] = (unsigned char)(int)(an * qs + 0.5f);
            P1[eb + (size_t)t*MQ + jown] = __logf(an) + C;
            __syncthreads();
        }
        if (tid == 0) {
            llws[m*MB + b] = C;
            out[NPOST + m*MB + b] = C;
        }
    } else {
        // ================= backward =================
        float D = 0.f;
        {   // t = L-1: beta_hat = 1, P2 = 0, wl = E[L-1]
            float ev = Eb[(size_t)(ML-1)*MQ + jown];
            float c, mx;
            BLOCKRED(0.f, ev, c, mx);
            (void)c;
            float qs = 126.f / mx; inv_sa = mx * (1.f/126.f);
            ab[wslot] = (unsigned char)(int)(ev * qs + 0.5f);
            out[eb + (size_t)(ML-1)*MQ + jown] = 0.f;
            __syncthreads();
        }
        #pragma unroll 1
        for (int t = ML-2; t >= 0; --t) {
            float ev = Eb[(size_t)t*MQ + jown];
            int mvi;
            MATVEC_I8(mvi);
            float mv = (float)mvi * (rsj * inv_sa);
            float y = mv * ev;
            float c, mx;
            BLOCKRED(mv, y, c, mx);
            float ic = 1.f/c; D += __logf(c);
            float bn = mv * ic;
            float wv = y * ic, wmax = mx * ic;
            float qs = 126.f / wmax; inv_sa = wmax * (1.f/126.f);
            ab[wslot] = (unsigned char)(int)(wv * qs + 0.5f);
            out[eb + (size_t)t*MQ + jown] = __logf(bn) + D;
            __syncthreads();
        }
    }
}

// ---------------- combine: out = P2(out) + P1 - loglik ----------------
__global__ void k_combine(const float* __restrict__ P1, const float* __restrict__ llws,
                          float* __restrict__ out) {
    size_t idx = ((size_t)blockIdx.x * 256 + threadIdx.x) * 4;
    int mb = (int)(idx >> 18);                  // L*Q = 262144 per (m,b)
    float ll = llws[mb];
    float4 p = *(const float4*)(P1 + idx);
    float4 o = *(const float4*)(out + idx);
    o.x = o.x + p.x - ll;
    o.y = o.y + p.y - ll;
    o.z = o.z + p.z - ll;
    o.w = o.w + p.w - ll;
    *(float4*)(out + idx) = o;
}

extern "C" void kernel_launch(void* const* d_in, const int* in_sizes, int n_in,
                              void* d_out, int out_size, void* d_ws, size_t ws_size,
                              hipStream_t stream) {
    (void)in_sizes; (void)n_in; (void)out_size; (void)ws_size;
    const float* inp   = (const float*)d_in[0];
    const float* trans = (const float*)d_in[1];
    const float* emis  = (const float*)d_in[2];
    const float* initl = (const float*)d_in[3];
    float* out = (float*)d_out;
    float* ws  = (float*)d_ws;

    float*    wsA    = ws + OFF_A;
    unsigned* wsAQ8  = (unsigned*)(ws + OFF_AQ8);
    unsigned* wsATQ8 = (unsigned*)(ws + OFF_ATQ8);
    float*    wsCP   = ws + OFF_CP;
    float*    wsROWM = ws + OFF_ROWM;
    float*    wsSCA  = ws + OFF_SCA;
    float*    wsINVA = ws + OFF_INVA;
    float*    wsSCT  = ws + OFF_SCT;
    float*    wsINVT = ws + OFF_INVT;
    float*    wsB    = ws + OFF_B;
    float*    wsInit = ws + OFF_INIT;
    float*    wsE    = ws + OFF_E;
    float*    wsP1   = ws + OFF_P1;
    float*    wsLL   = ws + OFF_LL;

    (void)hipFuncSetAttribute((const void*)k_fwdbwd,
                              hipFuncAttributeMaxDynamicSharedMemorySize,
                              SHM_DYN);

    k_softmaxA<<<MM*MQ, 256, 0, stream>>>(trans, wsA);
    k_amaxc<<<dim3(16, MM), 512, 0, stream>>>(wsA, wsCP, wsROWM);
    k_amaxr<<<MM, 512, 0, stream>>>(wsCP, wsROWM, wsSCA, wsINVA, wsSCT, wsINVT);
    k_packA8<<<dim3(128, MM), 512, 0, stream>>>(wsA, wsSCA, wsAQ8);
    k_packAT8<<<dim3(8, 8, MM), dim3(64, 4), 0, stream>>>(wsA, wsSCT, wsATQ8);
    k_bprep<<<MM, 512, 0, stream>>>(emis, initl, wsB, wsInit);
    k_ekernel<<<dim3(ML/8, MB, MM), 512, 0, stream>>>(inp, wsB, wsE);
    k_fwdbwd<<<128, 512, SHM_DYN, stream>>>(wsAQ8, wsATQ8, wsINVA, wsINVT,
                                            wsE, wsInit, wsP1, out, wsLL);
    k_combine<<<NPOST/1024, 256, 0, stream>>>(wsP1, wsLL, out);
}